// Round 1
// baseline (1330.605 us; speedup 1.0000x reference)
//
#include <hip/hip_runtime.h>
#include <hip/hip_bf16.h>
#include <math.h>

#define Bb 32
#define Cc 512
#define HW 3136        // 56*56
#define HW4 784        // HW/4
#define G  32
#define GS 16
#define Nn (Bb*HW)     // 100352
#define EPSF 1e-3f
#define TRI 136        // 16*17/2
#define STATS (TRI+GS) // 152: [0..15] sums, [16..151] upper-tri cross products

typedef float floatx4 __attribute__((ext_vector_type(4)));

// upper-triangle pack (i<=j): idx = i*16 - i*(i+1)/2 + j, range 0..135
#define TIDX(i,j) ((i)*GS - (i)*((i)+1)/2 + (j))

// ---------------- Kernel 1: per-(b,g) partial sums + cross-products ----------------
// float4 loads: 4x fewer load instructions and 4x more VALU work per load-latency
// exposure (608 FMAs ~ 1216 cy covers ~900 cy HBM latency even at 2 waves/SIMD).
__global__ __launch_bounds__(256, 2) void stats_kernel(const float* __restrict__ x,
                                                       float* __restrict__ part) {
    const int blk = blockIdx.x;      // b*G + g
    const int b = blk / G;
    const int g = blk % G;
    const floatx4* __restrict__ xb4 = reinterpret_cast<const floatx4*>(
        x + ((size_t)b * Cc + (size_t)g * GS) * HW);

    float s[GS];
    float c[TRI];
#pragma unroll
    for (int i = 0; i < GS; i++) s[i] = 0.f;
#pragma unroll
    for (int i = 0; i < TRI; i++) c[i] = 0.f;

    for (int p = threadIdx.x; p < HW4; p += 256) {
        floatx4 v[GS];
#pragma unroll
        for (int j = 0; j < GS; j++) v[j] = xb4[(size_t)j * HW4 + p];
#pragma unroll
        for (int j = 0; j < GS; j++) s[j] += (v[j].x + v[j].y) + (v[j].z + v[j].w);
#pragma unroll
        for (int i = 0; i < GS; i++) {
#pragma unroll
            for (int j = i; j < GS; j++) {
                float acc = c[TIDX(i, j)];
                acc = fmaf(v[i].x, v[j].x, acc);
                acc = fmaf(v[i].y, v[j].y, acc);
                acc = fmaf(v[i].z, v[j].z, acc);
                acc = fmaf(v[i].w, v[j].w, acc);
                c[TIDX(i, j)] = acc;
            }
        }
    }

    // wave-level butterfly reduce (64 lanes)
#pragma unroll
    for (int m = 1; m < 64; m <<= 1) {
#pragma unroll
        for (int i = 0; i < GS; i++) s[i] += __shfl_xor(s[i], m, 64);
#pragma unroll
        for (int i = 0; i < TRI; i++) c[i] += __shfl_xor(c[i], m, 64);
    }

    __shared__ float red[4][STATS];
    const int wave = threadIdx.x >> 6;
    const int lane = threadIdx.x & 63;
    if (lane == 0) {
#pragma unroll
        for (int i = 0; i < GS; i++) red[wave][i] = s[i];
#pragma unroll
        for (int i = 0; i < TRI; i++) red[wave][GS + i] = c[i];
    }
    __syncthreads();
    if (threadIdx.x < STATS) {
        float t = red[0][threadIdx.x] + red[1][threadIdx.x] +
                  red[2][threadIdx.x] + red[3][threadIdx.x];
        part[((size_t)g * Bb + b) * STATS + threadIdx.x] = t;
    }
}

// ---------------- Kernel 2: reduce partials, Cholesky, invert, pack L^-1 + bias ----------------
// Register-resident parallel Cholesky (thread i owns row i; shfl broadcasts) and
// register-resident forward substitution (thread j owns column j) — replaces the
// serial thread-0 LDS-latency chain.
__global__ __launch_bounds__(64) void solve_kernel(const float* __restrict__ part,
                                                   float* __restrict__ wl) {
    const int g = blockIdx.x;
    const int t = threadIdx.x;

    __shared__ float st[STATS];
    __shared__ float Lsh[GS][GS + 1];
    __shared__ float Ish[GS][GS + 1];

    // reduce 32 per-batch partials (lanes coalesced across k)
    for (int k = t; k < STATS; k += 64) {
        float acc = 0.f;
#pragma unroll
        for (int b = 0; b < Bb; b++)
            acc += part[((size_t)g * Bb + b) * STATS + k];
        st[k] = acc;
    }
    __syncthreads();

    const float invN = 1.0f / (float)Nn;

    if (t < GS) {
        // thread i = t owns row i of the shrunken covariance in registers
        float A[GS];
        const float mi = st[t] * invN;
#pragma unroll
        for (int j = 0; j < GS; j++) {
            const int ii = t < j ? t : j;
            const int jj = t < j ? j : t;
            const float mj = st[j] * invN;
            float cv = st[GS + TIDX(ii, jj)] * invN - mi * mj;
            cv *= (1.0f - EPSF);
            if (j == t) cv += EPSF;
            A[j] = cv;
        }

        // right-looking Cholesky, rows distributed over lanes 0..15
#pragma unroll
        for (int k = 0; k < GS; k++) {
            const float dkk = __shfl(A[k], k, 64);  // updated a[k][k] from lane k
            const float d = sqrtf(dkk);
            const float lik = (t == k) ? d : A[k] / d;  // L[i][k] (valid for i>=k)
            A[k] = lik;
#pragma unroll
            for (int j = k + 1; j < GS; j++) {
                const float ljk = __shfl(A[k], j, 64);  // L[j][k] from lane j
                A[j] -= lik * ljk;  // meaningful for i >= j; junk above diag unused
            }
        }

        // publish L (row i = A[0..i]; above-diag junk never read)
#pragma unroll
        for (int j = 0; j < GS; j++) Lsh[t][j] = A[j];
    }
    __syncthreads();

    if (t < GS) {
        // forward substitution: thread j = t computes column j of L^-1 in registers
        const int j = t;
        float col[GS];
#pragma unroll
        for (int i = 0; i < GS; i++) col[i] = 0.f;
#pragma unroll
        for (int i = 0; i < GS; i++) {  // uniform loop; terms with k<j are zero
            float v = (i == j) ? 1.f : 0.f;
#pragma unroll
            for (int k = 0; k < i; k++) v -= Lsh[i][k] * col[k];
            col[i] = (i >= j) ? v / Lsh[i][i] : 0.f;
        }
#pragma unroll
        for (int i = 0; i < GS; i++) Ish[i][j] = col[i];
    }
    __syncthreads();

    // pack: wl[g][0..135] = lower-tri L^-1 (idx i*(i+1)/2+j), wl[g][136..151] = bias = L^-1 m
    float* wg = wl + (size_t)g * STATS;
    for (int e = t; e < GS * GS; e += 64) {
        const int i = e >> 4, j = e & 15;
        if (j <= i) wg[i * (i + 1) / 2 + j] = Ish[i][j];
    }
    if (t < GS) {
        float bias = 0.f;
#pragma unroll
        for (int j = 0; j < GS; j++) bias += Ish[t][j] * (st[j] * invN);  // zeros above diag
        wg[TRI + t] = bias;
    }
}

// ---------------- Kernel 3: out = L^-1 x - bias (float4, NT stores) ----------------
// L^-1 and bias staged in LDS (broadcast reads are conflict-free); keeps VGPRs for
// the 16 float4 x-values + pipelining instead of 152 pinned coefficient registers.
__global__ __launch_bounds__(256, 2) void apply_kernel(const float* __restrict__ x,
                                                       const float* __restrict__ wl,
                                                       float* __restrict__ out) {
    const int blk = blockIdx.x;   // b*G + g
    const int b = blk / G;
    const int g = blk % G;

    __shared__ float Ls[STATS];
    {
        const float* __restrict__ wg = wl + (size_t)g * STATS;
        for (int i = threadIdx.x; i < STATS; i += 256) Ls[i] = wg[i];
    }
    __syncthreads();

    const size_t base_off = ((size_t)b * Cc + (size_t)g * GS) * HW;
    const floatx4* __restrict__ xb4 = reinterpret_cast<const floatx4*>(x + base_off);
    floatx4* __restrict__ ob4 = reinterpret_cast<floatx4*>(out + base_off);

    for (int p = threadIdx.x; p < HW4; p += 256) {
        floatx4 v[GS];
#pragma unroll
        for (int j = 0; j < GS; j++) v[j] = xb4[(size_t)j * HW4 + p];
#pragma unroll
        for (int i = 0; i < GS; i++) {
            floatx4 o = (floatx4)(-Ls[TRI + i]);
#pragma unroll
            for (int j = 0; j <= i; j++) {
                o += Ls[i * (i + 1) / 2 + j] * v[j];
            }
            __builtin_nontemporal_store(o, &ob4[(size_t)i * HW4 + p]);
        }
    }
}

extern "C" void kernel_launch(void* const* d_in, const int* in_sizes, int n_in,
                              void* d_out, int out_size, void* d_ws, size_t ws_size,
                              hipStream_t stream) {
    const float* x = (const float*)d_in[0];
    float* out = (float*)d_out;

    float* part = (float*)d_ws;                         // G*Bb*STATS floats
    float* wl = part + (size_t)G * Bb * STATS;          // G*STATS floats

    stats_kernel<<<Bb * G, 256, 0, stream>>>(x, part);
    solve_kernel<<<G, 64, 0, stream>>>(part, wl);
    apply_kernel<<<Bb * G, 256, 0, stream>>>(x, wl, out);
}

// Round 2
// 425.406 us; speedup vs baseline: 3.1278x; 3.1278x over previous
//
#include <hip/hip_runtime.h>
#include <hip/hip_bf16.h>
#include <math.h>

#define Bb 32
#define Cc 512
#define HW 3136        // 56*56
#define HW4 784        // HW/4
#define G  32
#define GS 16
#define Nn (Bb*HW)     // 100352
#define EPSF 1e-3f
#define TRI 136        // 16*17/2
#define STATS (TRI+GS) // 152: [0..15] sums, [16..151] upper-tri cross products

typedef float floatx4 __attribute__((ext_vector_type(4)));

// upper-triangle pack (i<=j): idx = i*16 - i*(i+1)/2 + j, range 0..135
#define TIDX(i,j) ((i)*GS - (i)*((i)+1)/2 + (j))

// ---------------- Kernel 1: per-(b,g) partial sums + cross-products ----------------
// float4 loads (4x fewer load instrs, 4x VALU per latency exposure).
// NO min-waves launch bound: c[136]+s[16]+v[64] needs ~230 VGPR; capping at 128
// caused scratch spills in round 1. ~230 VGPR still gets 2 waves/SIMD (pool 512).
__global__ __launch_bounds__(256) void stats_kernel(const float* __restrict__ x,
                                                    float* __restrict__ part) {
    const int blk = blockIdx.x;      // b*G + g
    const int b = blk / G;
    const int g = blk % G;
    const floatx4* __restrict__ xb4 = reinterpret_cast<const floatx4*>(
        x + ((size_t)b * Cc + (size_t)g * GS) * HW);

    float s[GS];
    float c[TRI];
#pragma unroll
    for (int i = 0; i < GS; i++) s[i] = 0.f;
#pragma unroll
    for (int i = 0; i < TRI; i++) c[i] = 0.f;

    for (int p = threadIdx.x; p < HW4; p += 256) {
        floatx4 v[GS];
#pragma unroll
        for (int j = 0; j < GS; j++) v[j] = xb4[(size_t)j * HW4 + p];
#pragma unroll
        for (int j = 0; j < GS; j++) s[j] += (v[j].x + v[j].y) + (v[j].z + v[j].w);
#pragma unroll
        for (int i = 0; i < GS; i++) {
#pragma unroll
            for (int j = i; j < GS; j++) {
                float acc = c[TIDX(i, j)];
                acc = fmaf(v[i].x, v[j].x, acc);
                acc = fmaf(v[i].y, v[j].y, acc);
                acc = fmaf(v[i].z, v[j].z, acc);
                acc = fmaf(v[i].w, v[j].w, acc);
                c[TIDX(i, j)] = acc;
            }
        }
    }

    // wave-level butterfly reduce (64 lanes)
#pragma unroll
    for (int m = 1; m < 64; m <<= 1) {
#pragma unroll
        for (int i = 0; i < GS; i++) s[i] += __shfl_xor(s[i], m, 64);
#pragma unroll
        for (int i = 0; i < TRI; i++) c[i] += __shfl_xor(c[i], m, 64);
    }

    __shared__ float red[4][STATS];
    const int wave = threadIdx.x >> 6;
    const int lane = threadIdx.x & 63;
    if (lane == 0) {
#pragma unroll
        for (int i = 0; i < GS; i++) red[wave][i] = s[i];
#pragma unroll
        for (int i = 0; i < TRI; i++) red[wave][GS + i] = c[i];
    }
    __syncthreads();
    if (threadIdx.x < STATS) {
        float t = red[0][threadIdx.x] + red[1][threadIdx.x] +
                  red[2][threadIdx.x] + red[3][threadIdx.x];
        part[((size_t)g * Bb + b) * STATS + threadIdx.x] = t;
    }
}

// ---------------- Kernel 2: reduce partials, Cholesky, invert, pack L^-1 + bias ----------------
// Register-resident parallel Cholesky (thread i owns row i; shfl broadcasts) and
// register-resident forward substitution (thread j owns column j).
__global__ __launch_bounds__(64) void solve_kernel(const float* __restrict__ part,
                                                   float* __restrict__ wl) {
    const int g = blockIdx.x;
    const int t = threadIdx.x;

    __shared__ float st[STATS];
    __shared__ float Lsh[GS][GS + 1];
    __shared__ float Ish[GS][GS + 1];

    // reduce 32 per-batch partials (lanes coalesced across k)
    for (int k = t; k < STATS; k += 64) {
        float acc = 0.f;
#pragma unroll
        for (int b = 0; b < Bb; b++)
            acc += part[((size_t)g * Bb + b) * STATS + k];
        st[k] = acc;
    }
    __syncthreads();

    const float invN = 1.0f / (float)Nn;

    if (t < GS) {
        // thread i = t owns row i of the shrunken covariance in registers
        float A[GS];
        const float mi = st[t] * invN;
#pragma unroll
        for (int j = 0; j < GS; j++) {
            const int ii = t < j ? t : j;
            const int jj = t < j ? j : t;
            const float mj = st[j] * invN;
            float cv = st[GS + TIDX(ii, jj)] * invN - mi * mj;
            cv *= (1.0f - EPSF);
            if (j == t) cv += EPSF;
            A[j] = cv;
        }

        // right-looking Cholesky, rows distributed over lanes 0..15
#pragma unroll
        for (int k = 0; k < GS; k++) {
            const float dkk = __shfl(A[k], k, 64);  // updated a[k][k] from lane k
            const float d = sqrtf(dkk);
            const float lik = (t == k) ? d : A[k] / d;  // L[i][k] (valid for i>=k)
            A[k] = lik;
#pragma unroll
            for (int j = k + 1; j < GS; j++) {
                const float ljk = __shfl(A[k], j, 64);  // L[j][k] from lane j
                A[j] -= lik * ljk;  // meaningful for i >= j; junk above diag unused
            }
        }

        // publish L (row i = A[0..i]; above-diag junk never read)
#pragma unroll
        for (int j = 0; j < GS; j++) Lsh[t][j] = A[j];
    }
    __syncthreads();

    if (t < GS) {
        // forward substitution: thread j = t computes column j of L^-1 in registers
        const int j = t;
        float col[GS];
#pragma unroll
        for (int i = 0; i < GS; i++) col[i] = 0.f;
#pragma unroll
        for (int i = 0; i < GS; i++) {  // uniform loop; terms with k<j are zero
            float v = (i == j) ? 1.f : 0.f;
#pragma unroll
            for (int k = 0; k < i; k++) v -= Lsh[i][k] * col[k];
            col[i] = (i >= j) ? v / Lsh[i][i] : 0.f;
        }
#pragma unroll
        for (int i = 0; i < GS; i++) Ish[i][j] = col[i];
    }
    __syncthreads();

    // pack: wl[g][0..135] = lower-tri L^-1 (idx i*(i+1)/2+j), wl[g][136..151] = bias = L^-1 m
    float* wg = wl + (size_t)g * STATS;
    for (int e = t; e < GS * GS; e += 64) {
        const int i = e >> 4, j = e & 15;
        if (j <= i) wg[i * (i + 1) / 2 + j] = Ish[i][j];
    }
    if (t < GS) {
        float bias = 0.f;
#pragma unroll
        for (int j = 0; j < GS; j++) bias += Ish[t][j] * (st[j] * invN);  // zeros above diag
        wg[TRI + t] = bias;
    }
}

// ---------------- Kernel 3: out = L^-1 x - bias (float4, NT stores) ----------------
// Round-0 form: block-uniform coefficient loads -> s_load promotion, coefficients
// live in SGPRs / rematerialize (NOT VGPRs, NOT LDS). Do not touch.
__global__ __launch_bounds__(256) void apply_kernel(const float* __restrict__ x,
                                                    const float* __restrict__ wl,
                                                    float* __restrict__ out) {
    const int blk = blockIdx.x;   // b*G + g
    const int b = blk / G;
    const int g = blk % G;

    const float* __restrict__ wg = wl + (size_t)g * STATS;
    // block-uniform loads -> expect s_load promotion
    float Lt[TRI];
    float bias[GS];
#pragma unroll
    for (int i = 0; i < TRI; i++) Lt[i] = wg[i];
#pragma unroll
    for (int i = 0; i < GS; i++) bias[i] = wg[TRI + i];

    const size_t base_off = ((size_t)b * Cc + (size_t)g * GS) * HW;
    const floatx4* __restrict__ xb4 = reinterpret_cast<const floatx4*>(x + base_off);
    floatx4* __restrict__ ob4 = reinterpret_cast<floatx4*>(out + base_off);

    for (int p = threadIdx.x; p < HW4; p += 256) {
        floatx4 v[GS];
#pragma unroll
        for (int j = 0; j < GS; j++) v[j] = xb4[(size_t)j * HW4 + p];
#pragma unroll
        for (int i = 0; i < GS; i++) {
            floatx4 o = (floatx4)(-bias[i]);
#pragma unroll
            for (int j = 0; j <= i; j++) {
                o += Lt[i * (i + 1) / 2 + j] * v[j];
            }
            __builtin_nontemporal_store(o, &ob4[(size_t)i * HW4 + p]);
        }
    }
}

extern "C" void kernel_launch(void* const* d_in, const int* in_sizes, int n_in,
                              void* d_out, int out_size, void* d_ws, size_t ws_size,
                              hipStream_t stream) {
    const float* x = (const float*)d_in[0];
    float* out = (float*)d_out;

    float* part = (float*)d_ws;                         // G*Bb*STATS floats
    float* wl = part + (size_t)G * Bb * STATS;          // G*STATS floats

    stats_kernel<<<Bb * G, 256, 0, stream>>>(x, part);
    solve_kernel<<<G, 64, 0, stream>>>(part, wl);
    apply_kernel<<<Bb * G, 256, 0, stream>>>(x, wl, out);
}

// Round 3
// 402.164 us; speedup vs baseline: 3.3086x; 1.0578x over previous
//
#include <hip/hip_runtime.h>
#include <hip/hip_bf16.h>
#include <math.h>

#define Bb 32
#define Cc 512
#define HW 3136        // 56*56
#define HW4 784        // HW/4
#define G  32
#define GS 16
#define Nn (Bb*HW)     // 100352
#define EPSF 1e-3f
#define TRI 136        // 16*17/2
#define STATS (TRI+GS) // 152: [0..15] sums, [16..151] upper-tri cross products

typedef float floatx4 __attribute__((ext_vector_type(4)));

// upper-triangle pack (i<=j): idx = i*16 - i*(i+1)/2 + j, range 0..135
#define TIDX(i,j) ((i)*GS - (i)*((i)+1)/2 + (j))

// Full 64-lane sum via DPP (VALU pipe only — no LDS pipe, no lgkmcnt).
// row_shr 1/2/4/8 reduce within each row of 16; row_bcast:15 merges rows
// 0->1 / 2->3; row_bcast:31 merges halves. Valid result in lane 63.
// GCNDPPCombine fuses mov_dpp+add into v_add_f32_dpp: 6 VALU per value.
__device__ __forceinline__ float wave_red_sum63(float x) {
    int t;
    t = __builtin_amdgcn_update_dpp(0, __builtin_bit_cast(int, x), 0x111, 0xf, 0xf, true); // row_shr:1
    x += __builtin_bit_cast(float, t);
    t = __builtin_amdgcn_update_dpp(0, __builtin_bit_cast(int, x), 0x112, 0xf, 0xf, true); // row_shr:2
    x += __builtin_bit_cast(float, t);
    t = __builtin_amdgcn_update_dpp(0, __builtin_bit_cast(int, x), 0x114, 0xf, 0xf, true); // row_shr:4
    x += __builtin_bit_cast(float, t);
    t = __builtin_amdgcn_update_dpp(0, __builtin_bit_cast(int, x), 0x118, 0xf, 0xf, true); // row_shr:8
    x += __builtin_bit_cast(float, t);
    t = __builtin_amdgcn_update_dpp(0, __builtin_bit_cast(int, x), 0x142, 0xf, 0xf, true); // row_bcast:15
    x += __builtin_bit_cast(float, t);
    t = __builtin_amdgcn_update_dpp(0, __builtin_bit_cast(int, x), 0x143, 0xf, 0xf, true); // row_bcast:31
    x += __builtin_bit_cast(float, t);
    return x;
}

// ---------------- Kernel 1: per-(b,g) partial sums + cross-products ----------------
__global__ __launch_bounds__(256) void stats_kernel(const float* __restrict__ x,
                                                    float* __restrict__ part) {
    const int blk = blockIdx.x;      // b*G + g
    const int b = blk / G;
    const int g = blk % G;
    const floatx4* __restrict__ xb4 = reinterpret_cast<const floatx4*>(
        x + ((size_t)b * Cc + (size_t)g * GS) * HW);

    float s[GS];
    float c[TRI];
#pragma unroll
    for (int i = 0; i < GS; i++) s[i] = 0.f;
#pragma unroll
    for (int i = 0; i < TRI; i++) c[i] = 0.f;

    for (int p = threadIdx.x; p < HW4; p += 256) {
        floatx4 v[GS];
#pragma unroll
        for (int j = 0; j < GS; j++) v[j] = xb4[(size_t)j * HW4 + p];
#pragma unroll
        for (int j = 0; j < GS; j++) s[j] += (v[j].x + v[j].y) + (v[j].z + v[j].w);
#pragma unroll
        for (int i = 0; i < GS; i++) {
#pragma unroll
            for (int j = i; j < GS; j++) {
                float acc = c[TIDX(i, j)];
                acc = fmaf(v[i].x, v[j].x, acc);
                acc = fmaf(v[i].y, v[j].y, acc);
                acc = fmaf(v[i].z, v[j].z, acc);
                acc = fmaf(v[i].w, v[j].w, acc);
                c[TIDX(i, j)] = acc;
            }
        }
    }

    // wave reduce on the VALU pipe (DPP); result lands in lane 63 of each wave
#pragma unroll
    for (int i = 0; i < GS; i++) s[i] = wave_red_sum63(s[i]);
#pragma unroll
    for (int i = 0; i < TRI; i++) c[i] = wave_red_sum63(c[i]);

    __shared__ float red[4][STATS];
    const int wave = threadIdx.x >> 6;
    const int lane = threadIdx.x & 63;
    if (lane == 63) {
#pragma unroll
        for (int i = 0; i < GS; i++) red[wave][i] = s[i];
#pragma unroll
        for (int i = 0; i < TRI; i++) red[wave][GS + i] = c[i];
    }
    __syncthreads();
    if (threadIdx.x < STATS) {
        float t = red[0][threadIdx.x] + red[1][threadIdx.x] +
                  red[2][threadIdx.x] + red[3][threadIdx.x];
        part[((size_t)g * Bb + b) * STATS + threadIdx.x] = t;
    }
}

// ---------------- Kernel 2: reduce partials, Cholesky, invert, pack L^-1 + bias ----------------
// Register-resident parallel Cholesky (thread i owns row i; shfl broadcasts) and
// register-resident forward substitution (thread j owns column j).
__global__ __launch_bounds__(64) void solve_kernel(const float* __restrict__ part,
                                                   float* __restrict__ wl) {
    const int g = blockIdx.x;
    const int t = threadIdx.x;

    __shared__ float st[STATS];
    __shared__ float Lsh[GS][GS + 1];
    __shared__ float Ish[GS][GS + 1];

    // reduce 32 per-batch partials (lanes coalesced across k)
    for (int k = t; k < STATS; k += 64) {
        float acc = 0.f;
#pragma unroll
        for (int b = 0; b < Bb; b++)
            acc += part[((size_t)g * Bb + b) * STATS + k];
        st[k] = acc;
    }
    __syncthreads();

    const float invN = 1.0f / (float)Nn;

    if (t < GS) {
        // thread i = t owns row i of the shrunken covariance in registers
        float A[GS];
        const float mi = st[t] * invN;
#pragma unroll
        for (int j = 0; j < GS; j++) {
            const int ii = t < j ? t : j;
            const int jj = t < j ? j : t;
            const float mj = st[j] * invN;
            float cv = st[GS + TIDX(ii, jj)] * invN - mi * mj;
            cv *= (1.0f - EPSF);
            if (j == t) cv += EPSF;
            A[j] = cv;
        }

        // right-looking Cholesky, rows distributed over lanes 0..15
#pragma unroll
        for (int k = 0; k < GS; k++) {
            const float dkk = __shfl(A[k], k, 64);  // updated a[k][k] from lane k
            const float d = sqrtf(dkk);
            const float lik = (t == k) ? d : A[k] / d;  // L[i][k] (valid for i>=k)
            A[k] = lik;
#pragma unroll
            for (int j = k + 1; j < GS; j++) {
                const float ljk = __shfl(A[k], j, 64);  // L[j][k] from lane j
                A[j] -= lik * ljk;  // meaningful for i >= j; junk above diag unused
            }
        }

        // publish L (row i = A[0..i]; above-diag junk never read)
#pragma unroll
        for (int j = 0; j < GS; j++) Lsh[t][j] = A[j];
    }
    __syncthreads();

    if (t < GS) {
        // forward substitution: thread j = t computes column j of L^-1 in registers
        const int j = t;
        float col[GS];
#pragma unroll
        for (int i = 0; i < GS; i++) col[i] = 0.f;
#pragma unroll
        for (int i = 0; i < GS; i++) {  // uniform loop; terms with k<j are zero
            float v = (i == j) ? 1.f : 0.f;
#pragma unroll
            for (int k = 0; k < i; k++) v -= Lsh[i][k] * col[k];
            col[i] = (i >= j) ? v / Lsh[i][i] : 0.f;
        }
#pragma unroll
        for (int i = 0; i < GS; i++) Ish[i][j] = col[i];
    }
    __syncthreads();

    // pack: wl[g][0..135] = lower-tri L^-1 (idx i*(i+1)/2+j), wl[g][136..151] = bias = L^-1 m
    float* wg = wl + (size_t)g * STATS;
    for (int e = t; e < GS * GS; e += 64) {
        const int i = e >> 4, j = e & 15;
        if (j <= i) wg[i * (i + 1) / 2 + j] = Ish[i][j];
    }
    if (t < GS) {
        float bias = 0.f;
#pragma unroll
        for (int j = 0; j < GS; j++) bias += Ish[t][j] * (st[j] * invN);  // zeros above diag
        wg[TRI + t] = bias;
    }
}

// ---------------- Kernel 3: out = L^-1 x - bias (float4, NT stores) ----------------
// Block-uniform coefficient loads -> s_load promotion, coefficients in SGPRs.
// Round-0-proven form. Do not touch.
__global__ __launch_bounds__(256) void apply_kernel(const float* __restrict__ x,
                                                    const float* __restrict__ wl,
                                                    float* __restrict__ out) {
    const int blk = blockIdx.x;   // b*G + g
    const int b = blk / G;
    const int g = blk % G;

    const float* __restrict__ wg = wl + (size_t)g * STATS;
    // block-uniform loads -> expect s_load promotion
    float Lt[TRI];
    float bias[GS];
#pragma unroll
    for (int i = 0; i < TRI; i++) Lt[i] = wg[i];
#pragma unroll
    for (int i = 0; i < GS; i++) bias[i] = wg[TRI + i];

    const size_t base_off = ((size_t)b * Cc + (size_t)g * GS) * HW;
    const floatx4* __restrict__ xb4 = reinterpret_cast<const floatx4*>(x + base_off);
    floatx4* __restrict__ ob4 = reinterpret_cast<floatx4*>(out + base_off);

    for (int p = threadIdx.x; p < HW4; p += 256) {
        floatx4 v[GS];
#pragma unroll
        for (int j = 0; j < GS; j++) v[j] = xb4[(size_t)j * HW4 + p];
#pragma unroll
        for (int i = 0; i < GS; i++) {
            floatx4 o = (floatx4)(-bias[i]);
#pragma unroll
            for (int j = 0; j <= i; j++) {
                o += Lt[i * (i + 1) / 2 + j] * v[j];
            }
            __builtin_nontemporal_store(o, &ob4[(size_t)i * HW4 + p]);
        }
    }
}

extern "C" void kernel_launch(void* const* d_in, const int* in_sizes, int n_in,
                              void* d_out, int out_size, void* d_ws, size_t ws_size,
                              hipStream_t stream) {
    const float* x = (const float*)d_in[0];
    float* out = (float*)d_out;

    float* part = (float*)d_ws;                         // G*Bb*STATS floats
    float* wl = part + (size_t)G * Bb * STATS;          // G*STATS floats

    stats_kernel<<<Bb * G, 256, 0, stream>>>(x, part);
    solve_kernel<<<G, 64, 0, stream>>>(part, wl);
    apply_kernel<<<Bb * G, 256, 0, stream>>>(x, wl, out);
}

// Round 5
// 383.974 us; speedup vs baseline: 3.4654x; 1.0474x over previous
//
#include <hip/hip_runtime.h>
#include <hip/hip_bf16.h>
#include <math.h>

#define Bb 32
#define Cc 512
#define HW 3136        // 56*56
#define HW4 784        // HW/4
#define G  32
#define GS 16
#define Nn (Bb*HW)     // 100352
#define EPSF 1e-3f
#define TRI 136        // 16*17/2
#define STATS (TRI+GS) // 152: [0..15] sums, [16..151] upper-tri cross products
#define NCHUNK 98      // 3136 / 32 K-chunks per (b,g)

typedef float floatx4 __attribute__((ext_vector_type(4)));
typedef short bf16x8 __attribute__((ext_vector_type(8)));

// upper-triangle pack (i<=j): idx = i*16 - i*(i+1)/2 + j, range 0..135
#define TIDX(i,j) ((i)*GS - (i)*((i)+1)/2 + (j))

__device__ __forceinline__ unsigned short f32_bf16_rne(float f) {
    unsigned u = __builtin_bit_cast(unsigned, f);
    unsigned r = u + 0x7fffu + ((u >> 16) & 1u);
    return (unsigned short)(r >> 16);
}
__device__ __forceinline__ float bf16_f32(unsigned short h) {
    unsigned u = ((unsigned)h) << 16;
    return __builtin_bit_cast(float, u);
}

// ---------------- Kernel 1: per-(b,g) stats via bf16 hi/lo split MFMA SYRK ----------------
// cov*N = Hi·Hi^T + (Hi·Lo^T + (Hi·Lo^T)^T)  [lo·lo ~2^-18 rel, dropped]
// Accumulators live in 8 VGPRs (two f32x4 MFMA frags) instead of 136 scalars ->
// ~8 waves/SIMD occupancy -> latency actually hidden. Mean summed in exact f32.
__global__ __launch_bounds__(512, 8) void stats_kernel(const float* __restrict__ x,
                                                       float* __restrict__ part) {
    const int blk = blockIdx.x;      // b*G + g
    const int b = blk / G;
    const int g = blk % G;
    const int tid = threadIdx.x;
    const int w = tid >> 6;          // wave 0..7
    const int lane = tid & 63;
    const int row = lane & 15;       // A-row / B-col for this lane
    const int kgrp = lane >> 4;      // 0..3: which 8-wide K slice

    const float* __restrict__ base =
        x + ((size_t)b * Cc + (size_t)g * GS + row) * HW + kgrp * 8;

    floatx4 acc_hh = {0.f, 0.f, 0.f, 0.f};
    floatx4 acc_hl = {0.f, 0.f, 0.f, 0.f};
    float s_acc = 0.f;

    for (int t = w; t < NCHUNK; t += 8) {
        const float* p = base + t * 32;
        const floatx4 v0 = *reinterpret_cast<const floatx4*>(p);
        const floatx4 v1 = *reinterpret_cast<const floatx4*>(p + 4);

        bf16x8 hi, lo;
#pragma unroll
        for (int e = 0; e < 8; e++) {
            const float f = (e < 4) ? v0[e] : v1[e - 4];
            const unsigned short hb = f32_bf16_rne(f);
            const float lf = f - bf16_f32(hb);
            hi[e] = (short)hb;
            lo[e] = (short)f32_bf16_rne(lf);
            s_acc += f;
        }
        acc_hh = __builtin_amdgcn_mfma_f32_16x16x32_bf16(hi, hi, acc_hh, 0, 0, 0);
        acc_hl = __builtin_amdgcn_mfma_f32_16x16x32_bf16(hi, lo, acc_hl, 0, 0, 0);
    }

    // exact-f32 row sums: fold the 4 K-groups (lanes share row when l&15 equal)
    s_acc += __shfl_xor(s_acc, 16, 64);
    s_acc += __shfl_xor(s_acc, 32, 64);

    // per-wave fragments -> LDS; C/D layout: col = lane&15, row = (lane>>4)*4 + r
    __shared__ float lds_hh[8][GS][GS];
    __shared__ float lds_hl[8][GS][GS];
    __shared__ float lds_s[8][GS];
#pragma unroll
    for (int r = 0; r < 4; r++) {
        lds_hh[w][kgrp * 4 + r][row] = acc_hh[r];
        lds_hl[w][kgrp * 4 + r][row] = acc_hl[r];
    }
    if (lane < GS) lds_s[w][lane] = s_acc;
    __syncthreads();

    // reduce 8 waves, symmetrize HL, pack upper-tri + sums
    float* __restrict__ pb = part + ((size_t)g * Bb + b) * STATS;
    if (tid < 256) {
        const int i = tid >> 4, j = tid & 15;
        if (j >= i) {
            float v = 0.f;
#pragma unroll
            for (int ww = 0; ww < 8; ww++)
                v += lds_hh[ww][i][j] + lds_hl[ww][i][j] + lds_hl[ww][j][i];
            pb[GS + TIDX(i, j)] = v;
        }
        if (tid < GS) {
            float sv = 0.f;
#pragma unroll
            for (int ww = 0; ww < 8; ww++) sv += lds_s[ww][tid];
            pb[tid] = sv;
        }
    }
}

// ---------------- Kernel 2: reduce partials, Cholesky, invert, pack L^-1 + bias ----------------
// Register-resident parallel Cholesky (thread i owns row i; shfl broadcasts) and
// register-resident forward substitution (thread j owns column j).
__global__ __launch_bounds__(64) void solve_kernel(const float* __restrict__ part,
                                                   float* __restrict__ wl) {
    const int g = blockIdx.x;
    const int t = threadIdx.x;

    __shared__ float st[STATS];
    __shared__ float Lsh[GS][GS + 1];
    __shared__ float Ish[GS][GS + 1];

    // reduce 32 per-batch partials (lanes coalesced across k)
    for (int k = t; k < STATS; k += 64) {
        float acc = 0.f;
#pragma unroll
        for (int b = 0; b < Bb; b++)
            acc += part[((size_t)g * Bb + b) * STATS + k];
        st[k] = acc;
    }
    __syncthreads();

    const float invN = 1.0f / (float)Nn;

    if (t < GS) {
        // thread i = t owns row i of the shrunken covariance in registers
        float A[GS];
        const float mi = st[t] * invN;
#pragma unroll
        for (int j = 0; j < GS; j++) {
            const int ii = t < j ? t : j;
            const int jj = t < j ? j : t;
            const float mj = st[j] * invN;
            float cv = st[GS + TIDX(ii, jj)] * invN - mi * mj;
            cv *= (1.0f - EPSF);
            if (j == t) cv += EPSF;
            A[j] = cv;
        }

        // right-looking Cholesky, rows distributed over lanes 0..15
#pragma unroll
        for (int k = 0; k < GS; k++) {
            const float dkk = __shfl(A[k], k, 64);  // updated a[k][k] from lane k
            const float d = sqrtf(dkk);
            const float lik = (t == k) ? d : A[k] / d;  // L[i][k] (valid for i>=k)
            A[k] = lik;
#pragma unroll
            for (int j = k + 1; j < GS; j++) {
                const float ljk = __shfl(A[k], j, 64);  // L[j][k] from lane j
                A[j] -= lik * ljk;  // meaningful for i >= j; junk above diag unused
            }
        }

        // publish L (row i = A[0..i]; above-diag junk never read)
#pragma unroll
        for (int j = 0; j < GS; j++) Lsh[t][j] = A[j];
    }
    __syncthreads();

    if (t < GS) {
        // forward substitution: thread j = t computes column j of L^-1 in registers
        const int j = t;
        float col[GS];
#pragma unroll
        for (int i = 0; i < GS; i++) col[i] = 0.f;
#pragma unroll
        for (int i = 0; i < GS; i++) {  // uniform loop; terms with k<j are zero
            float v = (i == j) ? 1.f : 0.f;
#pragma unroll
            for (int k = 0; k < i; k++) v -= Lsh[i][k] * col[k];
            col[i] = (i >= j) ? v / Lsh[i][i] : 0.f;
        }
#pragma unroll
        for (int i = 0; i < GS; i++) Ish[i][j] = col[i];
    }
    __syncthreads();

    // pack: wl[g][0..135] = lower-tri L^-1 (idx i*(i+1)/2+j), wl[g][136..151] = bias = L^-1 m
    float* wg = wl + (size_t)g * STATS;
    for (int e = t; e < GS * GS; e += 64) {
        const int i = e >> 4, j = e & 15;
        if (j <= i) wg[i * (i + 1) / 2 + j] = Ish[i][j];
    }
    if (t < GS) {
        float bias = 0.f;
#pragma unroll
        for (int j = 0; j < GS; j++) bias += Ish[t][j] * (st[j] * invN);  // zeros above diag
        wg[TRI + t] = bias;
    }
}

// ---------------- Kernel 3: out = L^-1 x - bias (float4, NT stores) ----------------
// Block-uniform coefficient loads -> s_load promotion, coefficients in SGPRs.
// Round-0-proven form. Do not touch.
__global__ __launch_bounds__(256) void apply_kernel(const float* __restrict__ x,
                                                    const float* __restrict__ wl,
                                                    float* __restrict__ out) {
    const int blk = blockIdx.x;   // b*G + g
    const int b = blk / G;
    const int g = blk % G;

    const float* __restrict__ wg = wl + (size_t)g * STATS;
    // block-uniform loads -> expect s_load promotion
    float Lt[TRI];
    float bias[GS];
#pragma unroll
    for (int i = 0; i < TRI; i++) Lt[i] = wg[i];
#pragma unroll
    for (int i = 0; i < GS; i++) bias[i] = wg[TRI + i];

    const size_t base_off = ((size_t)b * Cc + (size_t)g * GS) * HW;
    const floatx4* __restrict__ xb4 = reinterpret_cast<const floatx4*>(x + base_off);
    floatx4* __restrict__ ob4 = reinterpret_cast<floatx4*>(out + base_off);

    for (int p = threadIdx.x; p < HW4; p += 256) {
        floatx4 v[GS];
#pragma unroll
        for (int j = 0; j < GS; j++) v[j] = xb4[(size_t)j * HW4 + p];
#pragma unroll
        for (int i = 0; i < GS; i++) {
            floatx4 o = (floatx4)(-bias[i]);
#pragma unroll
            for (int j = 0; j <= i; j++) {
                o += Lt[i * (i + 1) / 2 + j] * v[j];
            }
            __builtin_nontemporal_store(o, &ob4[(size_t)i * HW4 + p]);
        }
    }
}

extern "C" void kernel_launch(void* const* d_in, const int* in_sizes, int n_in,
                              void* d_out, int out_size, void* d_ws, size_t ws_size,
                              hipStream_t stream) {
    const float* x = (const float*)d_in[0];
    float* out = (float*)d_out;

    float* part = (float*)d_ws;                         // G*Bb*STATS floats
    float* wl = part + (size_t)G * Bb * STATS;          // G*STATS floats

    stats_kernel<<<Bb * G, 512, 0, stream>>>(x, part);
    solve_kernel<<<G, 64, 0, stream>>>(part, wl);
    apply_kernel<<<Bb * G, 256, 0, stream>>>(x, wl, out);
}

// Round 9
// 382.469 us; speedup vs baseline: 3.4790x; 1.0039x over previous
//
#include <hip/hip_runtime.h>
#include <hip/hip_bf16.h>
#include <math.h>

#define Bb 32
#define Cc 512
#define HW 3136        // 56*56
#define HW4 784        // HW/4
#define G  32
#define GS 16
#define Nn (Bb*HW)     // 100352
#define EPSF 1e-3f
#define TRI 136        // 16*17/2
#define STATS (TRI+GS) // 152: [0..15] sums, [16..151] upper-tri cross products
#define NPAIR 49       // 3136 / 64 chunk-pairs per (b,g)

typedef float floatx4 __attribute__((ext_vector_type(4)));
typedef short bf16x8 __attribute__((ext_vector_type(8)));

// upper-triangle pack (i<=j): idx = i*16 - i*(i+1)/2 + j, range 0..135
#define TIDX(i,j) ((i)*GS - (i)*((i)+1)/2 + (j))

// 8x f32 -> hi/lo bf16 split. Uses __float2bfloat16 (RNE) so the compiler can
// pattern-match pairs into v_cvt_pk_bf16_f32 (m240: compiler beats hand asm).
__device__ __forceinline__ void cvt_hilo8(const floatx4 v0, const floatx4 v1,
                                          bf16x8* hi, bf16x8* lo) {
#pragma unroll
    for (int e = 0; e < 8; e++) {
        const float f = (e < 4) ? v0[e] : v1[e - 4];
        const __hip_bfloat16 h = __float2bfloat16(f);
        const __hip_bfloat16 l = __float2bfloat16(f - __bfloat162float(h));
        (*hi)[e] = __builtin_bit_cast(short, h);
        (*lo)[e] = __builtin_bit_cast(short, l);
    }
}

// ---------------- Kernel 1: per-(b,g) stats via bf16 hi/lo split MFMA SYRK ----------------
// cov*N = Hi·Hi^T + (Hi·Lo^T + (Hi·Lo^T)^T)  [lo·lo ~2^-18 rel, dropped]
// Per iteration: one chunk-PAIR (64 B/lane: 4x dwordx4 issued together) -> 4 MFMAs.
// No min-wave cap: let the allocator use ~80 VGPR for load pipelining (~6 waves/SIMD).
__global__ __launch_bounds__(512) void stats_kernel(const float* __restrict__ x,
                                                    float* __restrict__ part) {
    const int blk = blockIdx.x;      // b*G + g
    const int b = blk / G;
    const int g = blk % G;
    const int tid = threadIdx.x;
    const int w = tid >> 6;          // wave 0..7
    const int lane = tid & 63;
    const int row = lane & 15;       // A-row / B-col for this lane
    const int kgrp = lane >> 4;      // 0..3: which 8-wide K slice

    const float* __restrict__ base =
        x + ((size_t)b * Cc + (size_t)g * GS + row) * HW + kgrp * 8;

    floatx4 acc_hh = {0.f, 0.f, 0.f, 0.f};
    floatx4 acc_hl = {0.f, 0.f, 0.f, 0.f};
    float s_acc = 0.f;

    for (int t = w; t < NPAIR; t += 8) {
        const float* p = base + (size_t)t * 64;
        const floatx4 a0 = *reinterpret_cast<const floatx4*>(p);
        const floatx4 a1 = *reinterpret_cast<const floatx4*>(p + 4);
        const floatx4 b0 = *reinterpret_cast<const floatx4*>(p + 32);
        const floatx4 b1 = *reinterpret_cast<const floatx4*>(p + 36);

        bf16x8 hiA, loA, hiB, loB;
        cvt_hilo8(a0, a1, &hiA, &loA);
        cvt_hilo8(b0, b1, &hiB, &loB);

        acc_hh = __builtin_amdgcn_mfma_f32_16x16x32_bf16(hiA, hiA, acc_hh, 0, 0, 0);
        acc_hl = __builtin_amdgcn_mfma_f32_16x16x32_bf16(hiA, loA, acc_hl, 0, 0, 0);
        acc_hh = __builtin_amdgcn_mfma_f32_16x16x32_bf16(hiB, hiB, acc_hh, 0, 0, 0);
        acc_hl = __builtin_amdgcn_mfma_f32_16x16x32_bf16(hiB, loB, acc_hl, 0, 0, 0);

        const floatx4 sv = (a0 + a1) + (b0 + b1);
        s_acc += (sv.x + sv.y) + (sv.z + sv.w);
    }

    // exact-f32 row sums: fold the 4 K-groups (lanes share row when l&15 equal)
    s_acc += __shfl_xor(s_acc, 16, 64);
    s_acc += __shfl_xor(s_acc, 32, 64);

    // per-wave fragments -> LDS; C/D layout: col = lane&15, row = (lane>>4)*4 + r
    __shared__ float lds_hh[8][GS][GS];
    __shared__ float lds_hl[8][GS][GS];
    __shared__ float lds_s[8][GS];
#pragma unroll
    for (int r = 0; r < 4; r++) {
        lds_hh[w][kgrp * 4 + r][row] = acc_hh[r];
        lds_hl[w][kgrp * 4 + r][row] = acc_hl[r];
    }
    if (lane < GS) lds_s[w][lane] = s_acc;
    __syncthreads();

    // reduce 8 waves, symmetrize HL, pack upper-tri + sums
    float* __restrict__ pb = part + ((size_t)g * Bb + b) * STATS;
    if (tid < 256) {
        const int i = tid >> 4, j = tid & 15;
        if (j >= i) {
            float v = 0.f;
#pragma unroll
            for (int ww = 0; ww < 8; ww++)
                v += lds_hh[ww][i][j] + lds_hl[ww][i][j] + lds_hl[ww][j][i];
            pb[GS + TIDX(i, j)] = v;
        }
        if (tid < GS) {
            float sv = 0.f;
#pragma unroll
            for (int ww = 0; ww < 8; ww++) sv += lds_s[ww][tid];
            pb[tid] = sv;
        }
    }
}

// ---------------- Kernel 2: reduce partials, Cholesky, invert, pack L^-1 + bias ----------------
// Register-resident parallel Cholesky (thread i owns row i; shfl broadcasts) and
// register-resident forward substitution (thread j owns column j).
__global__ __launch_bounds__(64) void solve_kernel(const float* __restrict__ part,
                                                   float* __restrict__ wl) {
    const int g = blockIdx.x;
    const int t = threadIdx.x;

    __shared__ float st[STATS];
    __shared__ float Lsh[GS][GS + 1];
    __shared__ float Ish[GS][GS + 1];

    // reduce 32 per-batch partials (lanes coalesced across k)
    for (int k = t; k < STATS; k += 64) {
        float acc = 0.f;
#pragma unroll
        for (int b = 0; b < Bb; b++)
            acc += part[((size_t)g * Bb + b) * STATS + k];
        st[k] = acc;
    }
    __syncthreads();

    const float invN = 1.0f / (float)Nn;

    if (t < GS) {
        // thread i = t owns row i of the shrunken covariance in registers
        float A[GS];
        const float mi = st[t] * invN;
#pragma unroll
        for (int j = 0; j < GS; j++) {
            const int ii = t < j ? t : j;
            const int jj = t < j ? j : t;
            const float mj = st[j] * invN;
            float cv = st[GS + TIDX(ii, jj)] * invN - mi * mj;
            cv *= (1.0f - EPSF);
            if (j == t) cv += EPSF;
            A[j] = cv;
        }

        // right-looking Cholesky, rows distributed over lanes 0..15
#pragma unroll
        for (int k = 0; k < GS; k++) {
            const float dkk = __shfl(A[k], k, 64);  // updated a[k][k] from lane k
            const float d = sqrtf(dkk);
            const float lik = (t == k) ? d : A[k] / d;  // L[i][k] (valid for i>=k)
            A[k] = lik;
#pragma unroll
            for (int j = k + 1; j < GS; j++) {
                const float ljk = __shfl(A[k], j, 64);  // L[j][k] from lane j
                A[j] -= lik * ljk;  // meaningful for i >= j; junk above diag unused
            }
        }

        // publish L (row i = A[0..i]; above-diag junk never read)
#pragma unroll
        for (int j = 0; j < GS; j++) Lsh[t][j] = A[j];
    }
    __syncthreads();

    if (t < GS) {
        // forward substitution: thread j = t computes column j of L^-1 in registers
        const int j = t;
        float col[GS];
#pragma unroll
        for (int i = 0; i < GS; i++) col[i] = 0.f;
#pragma unroll
        for (int i = 0; i < GS; i++) {  // uniform loop; terms with k<j are zero
            float v = (i == j) ? 1.f : 0.f;
#pragma unroll
            for (int k = 0; k < i; k++) v -= Lsh[i][k] * col[k];
            col[i] = (i >= j) ? v / Lsh[i][i] : 0.f;
        }
#pragma unroll
        for (int i = 0; i < GS; i++) Ish[i][j] = col[i];
    }
    __syncthreads();

    // pack: wl[g][0..135] = lower-tri L^-1 (idx i*(i+1)/2+j), wl[g][136..151] = bias = L^-1 m
    float* wg = wl + (size_t)g * STATS;
    for (int e = t; e < GS * GS; e += 64) {
        const int i = e >> 4, j = e & 15;
        if (j <= i) wg[i * (i + 1) / 2 + j] = Ish[i][j];
    }
    if (t < GS) {
        float bias = 0.f;
#pragma unroll
        for (int j = 0; j < GS; j++) bias += Ish[t][j] * (st[j] * invN);  // zeros above diag
        wg[TRI + t] = bias;
    }
}

// ---------------- Kernel 3: out = L^-1 x - bias (float4, NT stores) ----------------
// Block-uniform coefficient loads -> s_load promotion, coefficients in SGPRs.
// Round-0-proven form. Do not touch.
__global__ __launch_bounds__(256) void apply_kernel(const float* __restrict__ x,
                                                    const float* __restrict__ wl,
                                                    float* __restrict__ out) {
    const int blk = blockIdx.x;   // b*G + g
    const int b = blk / G;
    const int g = blk % G;

    const float* __restrict__ wg = wl + (size_t)g * STATS;
    // block-uniform loads -> expect s_load promotion
    float Lt[TRI];
    float bias[GS];
#pragma unroll
    for (int i = 0; i < TRI; i++) Lt[i] = wg[i];
#pragma unroll
    for (int i = 0; i < GS; i++) bias[i] = wg[TRI + i];

    const size_t base_off = ((size_t)b * Cc + (size_t)g * GS) * HW;
    const floatx4* __restrict__ xb4 = reinterpret_cast<const floatx4*>(x + base_off);
    floatx4* __restrict__ ob4 = reinterpret_cast<floatx4*>(out + base_off);

    for (int p = threadIdx.x; p < HW4; p += 256) {
        floatx4 v[GS];
#pragma unroll
        for (int j = 0; j < GS; j++) v[j] = xb4[(size_t)j * HW4 + p];
#pragma unroll
        for (int i = 0; i < GS; i++) {
            floatx4 o = (floatx4)(-bias[i]);
#pragma unroll
            for (int j = 0; j <= i; j++) {
                o += Lt[i * (i + 1) / 2 + j] * v[j];
            }
            __builtin_nontemporal_store(o, &ob4[(size_t)i * HW4 + p]);
        }
    }
}

extern "C" void kernel_launch(void* const* d_in, const int* in_sizes, int n_in,
                              void* d_out, int out_size, void* d_ws, size_t ws_size,
                              hipStream_t stream) {
    const float* x = (const float*)d_in[0];
    float* out = (float*)d_out;

    float* part = (float*)d_ws;                         // G*Bb*STATS floats
    float* wl = part + (size_t)G * Bb * STATS;          // G*STATS floats

    stats_kernel<<<Bb * G, 512, 0, stream>>>(x, part);
    solve_kernel<<<G, 64, 0, stream>>>(part, wl);
    apply_kernel<<<Bb * G, 256, 0, stream>>>(x, wl, out);
}